// Round 6
// baseline (49.483 us; speedup 1.0000x reference)
//
#include <hip/hip_runtime.h>
#include <hip/hip_bf16.h>

#define LOG2E 1.4426950408889634f
#define LN2   0.6931471805599453f

constexpr int Bn = 64, Sn = 512, Hn = 1024, Ln = 9;
constexpr int CL = 25;                 // emission steps per chunk
constexpr int NC = 21;                 // ceil((Sn-1)/CL) = 21 -> 3 waves x 7 units

typedef __attribute__((ext_vector_type(8))) short short8v;
typedef __attribute__((ext_vector_type(4))) float f32x4;

__device__ __forceinline__ float fexp2(float x) {
    float r; asm("v_exp_f32 %0, %1" : "=v"(r) : "v"(x)); return r;
}
__device__ __forceinline__ float flog2(float x) {
    float r; asm("v_log_f32 %0, %1" : "=v"(r) : "v"(x)); return r;
}
__device__ __forceinline__ unsigned cvtpk(float lo, float hi) {
    unsigned r; asm("v_cvt_pk_bf16_f32 %0, %1, %2" : "=v"(r) : "v"(lo), "v"(hi)); return r;
}
__device__ __forceinline__ float max9(const float* s) {
    return fmaxf(fmaxf(fmaxf(s[0], s[1]), fmaxf(s[2], s[3])),
                 fmaxf(fmaxf(s[4], s[5]), fmaxf(s[6], fmaxf(s[7], s[8]))));
}
__device__ __forceinline__ f32x4 nt4(const float* p) {
    return __builtin_nontemporal_load((const f32x4*)p);
}

// ============ Kernel 1: emissions = hidden @ W^T + b via bf16 MFMA ============
// 512 blocks x 256 thr (4 waves x 16 rows). W packed to LDS B-fragments; A loads
// software-pipelined 4 deep, first 4 iterations issued BEFORE the pack barrier.
// hidden loads are nontemporal (keep W resident in L2). Block (b,0) wave 0 also
// reduces mask -> slbuf[b] during the pre-barrier window.
__global__ __launch_bounds__(256) void emis_kernel(
    const float* __restrict__ hidden, const float* __restrict__ W,
    const float* __restrict__ bias,   const int* __restrict__ mask,
    float* __restrict__ emis, int* __restrict__ slbuf, float* __restrict__ out0)
{
    __shared__ __align__(16) unsigned short wfrag[32][64][8];  // [kstep][lane][e]
    const int tid = threadIdx.x, lane = tid & 63, w = tid >> 6;
    const int bid = blockIdx.x, b = bid >> 3, rb = bid & 7;

    if (bid == 0 && tid == 0) out0[0] = 0.f;      // loss accumulator init

    // pack W (fp32 9x1024) -> bf16 B-fragments, zero-pad cols 9..15
    for (int f = tid; f < 32 * 64; f += 256) {
        const int s = f >> 6, l = f & 63;
        const int j = l & 15, k0 = s * 32 + ((l >> 4) << 3);
        uint4 pk = {0u, 0u, 0u, 0u};
        if (j < Ln) {
            float4 a = *(const float4*)(W + j * Hn + k0);
            float4 c = *(const float4*)(W + j * Hn + k0 + 4);
            pk.x = cvtpk(a.x, a.y); pk.y = cvtpk(a.z, a.w);
            pk.z = cvtpk(c.x, c.y); pk.w = cvtpk(c.z, c.w);
        }
        *(uint4*)&wfrag[s][l][0] = pk;
    }

    // A-load pipeline: issue s=0..3 before the barrier (stream starts early)
    const int row0 = bid * 64 + w * 16;
    const float* hptr = hidden + (size_t)(row0 + (lane & 15)) * Hn + ((lane >> 4) << 3);
    f32x4 A[4][2];
    #pragma unroll
    for (int s = 0; s < 4; ++s) {
        A[s][0] = nt4(hptr + s * 32);
        A[s][1] = nt4(hptr + s * 32 + 4);
    }

    if (rb == 0 && w == 0) {                      // sequence length -> ws
        const int* mb = mask + b * Sn;
        int s = 0;
        #pragma unroll
        for (int r = 0; r < Sn / 64; ++r) s += mb[lane + r * 64];
        #pragma unroll
        for (int off = 32; off; off >>= 1) s += __shfl_xor(s, off);
        if (lane == 0) slbuf[b] = s;
    }
    __syncthreads();

    f32x4 acc = {0.f, 0.f, 0.f, 0.f};
    #pragma unroll 4
    for (int s = 0; s < 32; ++s) {
        f32x4 a0 = A[s & 3][0], a1 = A[s & 3][1];
        if (s < 28) {                             // refill slot s&3 for s+4
            A[s & 3][0] = nt4(hptr + (s + 4) * 32);
            A[s & 3][1] = nt4(hptr + (s + 4) * 32 + 4);
        }
        uint4 ap;
        ap.x = cvtpk(a0[0], a0[1]); ap.y = cvtpk(a0[2], a0[3]);
        ap.z = cvtpk(a1[0], a1[1]); ap.w = cvtpk(a1[2], a1[3]);
        short8v Av = *(short8v*)&ap;
        short8v Bv = *(const short8v*)&wfrag[s][lane][0];
        acc = __builtin_amdgcn_mfma_f32_16x16x32_bf16(Av, Bv, acc, 0, 0, 0);
    }

    const int col = lane & 15;
    if (col < Ln) {
        const float bv = bias[col];
        #pragma unroll
        for (int r = 0; r < 4; ++r) {
            const int row = ((lane >> 4) << 2) + r;
            emis[(size_t)(row0 + row) * Ln + col] = acc[r] + bv;
        }
    }
}

// ============ Kernel 2: fused CRF (chunks on waves 0-2, score on wave 3) ============
__global__ __launch_bounds__(256, 1) void crf_kernel(
    const float* __restrict__ emis, const float* __restrict__ st,
    const float* __restrict__ et,   const float* __restrict__ T,
    const int* __restrict__ labels, const int* __restrict__ slbuf,
    float* __restrict__ out)
{
    __shared__ __align__(16) float e_lds[Sn * Ln];   // raw emissions, 18432 B
    __shared__ float M_lds[NC][Ln][10];              // chunk matrices (log2 domain)
    __shared__ float part[1];

    const int b    = blockIdx.x;
    const int tid  = threadIdx.x;
    const int w    = tid >> 6;
    const int lane = tid & 63;

    // P0: stage emissions (issued first), E=exp(T) hides the latency, sl scalar
    {
        const float4* src = (const float4*)(emis + (size_t)b * Sn * Ln);
        float4* dst = (float4*)e_lds;
        for (int i = tid; i < (Sn * Ln) / 4; i += 256) dst[i] = src[i];
    }
    const int sl = slbuf[b];                    // >= 128
    float E[Ln][Ln];
    #pragma unroll
    for (int k = 0; k < Ln; ++k)
        #pragma unroll
        for (int j = 0; j < Ln; ++j)
            E[k][j] = fexp2(T[k * Ln + j] * LOG2E);
    __syncthreads();

    const int nreal = (sl - 1 + CL - 1) / CL;

    float logZ = 0.f;
    if (w < 3) {
        // P1a: chunk transfer matrices (9 lanes/unit, 7 units/wave, 21 units)
        const int ul = lane / 9;
        const int i  = lane - ul * 9;
        const int c  = w * 7 + ul;
        const int t0 = 1 + c * CL;
        if (ul < 7 && t0 < sl) {
            const int nst = min(CL, sl - t0);
            float u[Ln];
            {
                const float* e0 = e_lds + t0 * Ln;
                #pragma unroll
                for (int j = 0; j < Ln; ++j)
                    u[j] = E[i][j] * fexp2(fmaf(e0[j], LOG2E, -4.f));
            }
            float extra = 0.f;
            for (int s = 1; s < nst; ++s) {
                const float* es = e_lds + (t0 + s) * Ln;
                float e2[Ln];
                #pragma unroll
                for (int j = 0; j < Ln; ++j) e2[j] = es[j];   // issue before matvec
                float v[Ln];
                #pragma unroll
                for (int j = 0; j < Ln; ++j) v[j] = 0.f;
                #pragma unroll
                for (int kk = 0; kk < Ln; ++kk) {
                    const float uk = u[kk];
                    #pragma unroll
                    for (int j = 0; j < Ln; ++j)
                        v[j] = fmaf(uk, E[kk][j], v[j]);
                }
                #pragma unroll
                for (int j = 0; j < Ln; ++j)
                    u[j] = v[j] * fexp2(fmaf(e2[j], LOG2E, -4.f));
                if (s == 12) {                  // exponent-range insurance
                    float m  = max9(u);
                    float iv = 1.f / m;
                    #pragma unroll
                    for (int j = 0; j < Ln; ++j) u[j] *= iv;
                    extra = flog2(m);
                }
            }
            #pragma unroll
            for (int j = 0; j < Ln; ++j)
                M_lds[c][i][j] = flog2(u[j]) + extra + 4.f * (float)nst;
        }
    } else {
        // P1b: numerator score, overlapped with the chunk phase
        const int* lb = labels + b * Sn;
        float sc = 0.f;
        for (int t = lane; t < sl; t += 64) {
            int lt = lb[t];
            sc += e_lds[t * Ln + lt];
            if (t >= 1) sc += T[lb[t - 1] * Ln + lt];
        }
        #pragma unroll
        for (int off = 32; off; off >>= 1) sc += __shfl_xor(sc, off);
        if (lane == 0) part[0] = sc + st[lb[0]] + et[lb[sl - 1]];
    }
    __syncthreads();

    // P2: wave 0 combines the chunk matrices and emits the loss term
    if (w == 0) {
        const int j9 = lane < Ln ? lane : Ln - 1;
        float al[Ln];
        #pragma unroll
        for (int j = 0; j < Ln; ++j) al[j] = (st[j] + e_lds[j]) * LOG2E;
        for (int c = 0; c < nreal; ++c) {
            float s[Ln];
            #pragma unroll
            for (int k = 0; k < Ln; ++k) s[k] = al[k] + M_lds[c][k][j9];
            float p = max9(s);
            float sum = fexp2(s[0] - p);
            #pragma unroll
            for (int k = 1; k < Ln; ++k) sum += fexp2(s[k] - p);
            float aj = p + flog2(sum);
            #pragma unroll
            for (int k = 0; k < Ln; ++k) al[k] = __shfl(aj, k);
        }
        float z[Ln];
        #pragma unroll
        for (int j = 0; j < Ln; ++j) z[j] = al[j] + et[j] * LOG2E;
        float p = max9(z);
        float sum = fexp2(z[0] - p);
        #pragma unroll
        for (int j = 1; j < Ln; ++j) sum += fexp2(z[j] - p);
        logZ = (p + flog2(sum)) * LN2;

        if (lane == 0) {
            float llh = part[0] - logZ;
            atomicAdd(out, llh * (-1.f / 64.f));
        }
    }
}

extern "C" void kernel_launch(void* const* d_in, const int* in_sizes, int n_in,
                              void* d_out, int out_size, void* d_ws, size_t ws_size,
                              hipStream_t stream) {
    const float* hidden = (const float*)d_in[0];
    const float* W      = (const float*)d_in[1];
    const float* bias   = (const float*)d_in[2];
    const float* st     = (const float*)d_in[3];
    const float* et     = (const float*)d_in[4];
    const float* T      = (const float*)d_in[5];
    const int*   labels = (const int*)d_in[6];
    const int*   mask   = (const int*)d_in[7];

    float* emis  = (float*)d_ws;                      // 32768 * 9 floats
    int*   slbuf = (int*)(emis + (size_t)Bn * Sn * Ln);
    float* outp  = (float*)d_out;

    emis_kernel<<<512, 256, 0, stream>>>(hidden, W, bias, mask, emis, slbuf, outp);
    crf_kernel<<<Bn, 256, 0, stream>>>(emis, st, et, T, labels, slbuf, outp);
}

// Round 7
// 45.248 us; speedup vs baseline: 1.0936x; 1.0936x over previous
//
#include <hip/hip_runtime.h>
#include <hip/hip_bf16.h>

#define LOG2E 1.4426950408889634f
#define LN2   0.6931471805599453f

constexpr int Bn = 64, Sn = 512, Hn = 1024, Ln = 9;
constexpr int CL = 24;                 // emission steps per chunk
constexpr int NC = 22;                 // ceil((Sn-1)/CL)

typedef __attribute__((ext_vector_type(8))) short short8v;
typedef __attribute__((ext_vector_type(4))) float f32x4;

__device__ __forceinline__ float fexp2(float x) {
    float r; asm("v_exp_f32 %0, %1" : "=v"(r) : "v"(x)); return r;
}
__device__ __forceinline__ float flog2(float x) {
    float r; asm("v_log_f32 %0, %1" : "=v"(r) : "v"(x)); return r;
}
__device__ __forceinline__ unsigned cvtpk(float lo, float hi) {
    unsigned r; asm("v_cvt_pk_bf16_f32 %0, %1, %2" : "=v"(r) : "v"(lo), "v"(hi)); return r;
}
__device__ __forceinline__ float max9(const float* s) {
    return fmaxf(fmaxf(fmaxf(s[0], s[1]), fmaxf(s[2], s[3])),
                 fmaxf(fmaxf(s[4], s[5]), fmaxf(s[6], fmaxf(s[7], s[8]))));
}

// ============ Kernel 1: emissions = hidden @ W^T + b via bf16 MFMA ============
// 512 blocks x 256 thr (4 waves x 16 rows). NO LDS, NO barrier: B-fragments are
// read per-lane directly from W (L2-resident, 36 KB) and packed to bf16 on the
// fly; A-fragments likewise from the hidden stream. Pure streaming kernel.
// Fragment layout (16x16x32 bf16): A row = lane&15, k = 8*(lane>>4)+e;
// B col = lane&15 (cols 9..15 clamped to W row 8 -> never stored);
// D col = lane&15, row = 4*(lane>>4)+reg (m89/m91 verified mapping).
__global__ __launch_bounds__(256) void emis_kernel(
    const float* __restrict__ hidden, const float* __restrict__ W,
    const float* __restrict__ bias, float* __restrict__ emis,
    float* __restrict__ out0)
{
    const int tid = threadIdx.x, lane = tid & 63, w = tid >> 6;

    if (blockIdx.x == 0 && tid == 0) out0[0] = 0.f;   // loss accumulator init

    const int row0 = blockIdx.x * 64 + w * 16;
    const int col  = lane & 15;
    const int k0   = (lane >> 4) << 3;
    const float* hptr = hidden + (size_t)(row0 + col) * Hn + k0;
    const float* wptr = W + (size_t)(col < Ln ? col : Ln - 1) * Hn + k0;

    f32x4 acc = {0.f, 0.f, 0.f, 0.f};
    #pragma unroll 4
    for (int s = 0; s < 32; ++s) {
        f32x4 a0 = *(const f32x4*)(hptr + s * 32);
        f32x4 a1 = *(const f32x4*)(hptr + s * 32 + 4);
        f32x4 b0 = *(const f32x4*)(wptr + s * 32);
        f32x4 b1 = *(const f32x4*)(wptr + s * 32 + 4);
        uint4 ap, bp;
        ap.x = cvtpk(a0[0], a0[1]); ap.y = cvtpk(a0[2], a0[3]);
        ap.z = cvtpk(a1[0], a1[1]); ap.w = cvtpk(a1[2], a1[3]);
        bp.x = cvtpk(b0[0], b0[1]); bp.y = cvtpk(b0[2], b0[3]);
        bp.z = cvtpk(b1[0], b1[1]); bp.w = cvtpk(b1[2], b1[3]);
        short8v Av = *(short8v*)&ap;
        short8v Bv = *(short8v*)&bp;
        acc = __builtin_amdgcn_mfma_f32_16x16x32_bf16(Av, Bv, acc, 0, 0, 0);
    }

    if (col < Ln) {
        const float bv = bias[col];
        #pragma unroll
        for (int r = 0; r < 4; ++r) {
            const int row = ((lane >> 4) << 2) + r;
            emis[(size_t)(row0 + row) * Ln + col] = acc[r] + bv;
        }
    }
}

// ============ Kernel 2: fused CRF (R5 known-good version, verbatim) ============
__global__ __launch_bounds__(256, 1) void crf_kernel(
    const float* __restrict__ emis, const float* __restrict__ st,
    const float* __restrict__ et,   const float* __restrict__ T,
    const int* __restrict__ labels, const int* __restrict__ mask,
    float* __restrict__ out)
{
    __shared__ __align__(16) float e_lds[Sn * Ln];   // raw emissions, 18432 B
    __shared__ float M_lds[NC][Ln][10];              // chunk matrices (log2 domain)
    __shared__ float part[4];
    __shared__ int   sl_sh;

    const int b    = blockIdx.x;
    const int tid  = threadIdx.x;
    const int w    = tid >> 6;
    const int lane = tid & 63;

    // P0: stage emissions + E=exp(T) (registers) + sequence length
    {
        const float4* src = (const float4*)(emis + (size_t)b * Sn * Ln);
        float4* dst = (float4*)e_lds;
        for (int i = tid; i < (Sn * Ln) / 4; i += 256) dst[i] = src[i];
    }
    float E[Ln][Ln];
    #pragma unroll
    for (int k = 0; k < Ln; ++k)
        #pragma unroll
        for (int j = 0; j < Ln; ++j)
            E[k][j] = fexp2(T[k * Ln + j] * LOG2E);
    if (w == 3) {
        const int* mb = mask + b * Sn;
        int s = 0;
        #pragma unroll
        for (int r = 0; r < Sn / 64; ++r) s += mb[lane + r * 64];
        #pragma unroll
        for (int off = 32; off; off >>= 1) s += __shfl_xor(s, off);
        if (lane == 0) sl_sh = s;
    }
    __syncthreads();

    const int sl    = sl_sh;                    // >= 128
    const int nreal = (sl - 1 + CL - 1) / CL;

    // P1: chunk transfer matrices (9 lanes/unit, 7 units/wave, 22 units live)
    {
        const int ul = lane / 9;
        const int i  = lane - ul * 9;
        const int c  = w * 7 + ul;
        const int t0 = 1 + c * CL;
        if (ul < 7 && c < nreal) {
            const int nst = min(CL, sl - t0);
            float u[Ln];
            {
                const float* e0 = e_lds + t0 * Ln;
                #pragma unroll
                for (int j = 0; j < Ln; ++j)
                    u[j] = E[i][j] * fexp2(fmaf(e0[j], LOG2E, -4.f));
            }
            float extra = 0.f;
            for (int s = 1; s < nst; ++s) {
                const float* es = e_lds + (t0 + s) * Ln;
                float e2[Ln];
                #pragma unroll
                for (int j = 0; j < Ln; ++j) e2[j] = es[j];   // issue before matvec
                float v[Ln];
                #pragma unroll
                for (int j = 0; j < Ln; ++j) v[j] = 0.f;
                #pragma unroll
                for (int kk = 0; kk < Ln; ++kk) {
                    const float uk = u[kk];
                    #pragma unroll
                    for (int j = 0; j < Ln; ++j)
                        v[j] = fmaf(uk, E[kk][j], v[j]);
                }
                #pragma unroll
                for (int j = 0; j < Ln; ++j)
                    u[j] = v[j] * fexp2(fmaf(e2[j], LOG2E, -4.f));
                if (s == 12) {                  // exponent-range insurance
                    float m  = max9(u);
                    float iv = 1.f / m;
                    #pragma unroll
                    for (int j = 0; j < Ln; ++j) u[j] *= iv;
                    extra = flog2(m);
                }
            }
            #pragma unroll
            for (int j = 0; j < Ln; ++j)
                M_lds[c][i][j] = flog2(u[j]) + extra + 4.f * (float)nst;
        }
    }
    __syncthreads();

    // P2: wave 0 = combine; waves 1-3 = numerator score
    float logZ = 0.f;
    if (w == 0) {
        const int j9 = lane < Ln ? lane : Ln - 1;
        float al[Ln];
        #pragma unroll
        for (int j = 0; j < Ln; ++j) al[j] = (st[j] + e_lds[j]) * LOG2E;
        for (int c = 0; c < nreal; ++c) {
            float s[Ln];
            #pragma unroll
            for (int k = 0; k < Ln; ++k) s[k] = al[k] + M_lds[c][k][j9];
            float p = max9(s);
            float sum = fexp2(s[0] - p);
            #pragma unroll
            for (int k = 1; k < Ln; ++k) sum += fexp2(s[k] - p);
            float aj = p + flog2(sum);
            #pragma unroll
            for (int k = 0; k < Ln; ++k) al[k] = __shfl(aj, k);
        }
        float z[Ln];
        #pragma unroll
        for (int j = 0; j < Ln; ++j) z[j] = al[j] + et[j] * LOG2E;
        float p = max9(z);
        float sum = fexp2(z[0] - p);
        #pragma unroll
        for (int j = 1; j < Ln; ++j) sum += fexp2(z[j] - p);
        logZ = (p + flog2(sum)) * LN2;
    } else {
        const int* lb = labels + b * Sn;
        float sc = 0.f;
        for (int t = (w - 1) * 64 + lane; t < sl; t += 192) {
            int lt = lb[t];
            sc += e_lds[t * Ln + lt];
            if (t >= 1) sc += T[lb[t - 1] * Ln + lt];
        }
        #pragma unroll
        for (int off = 32; off; off >>= 1) sc += __shfl_xor(sc, off);
        if (w == 1 && lane == 0) sc += st[lb[0]] + et[lb[sl - 1]];
        if (lane == 0) part[w - 1] = sc;
    }
    __syncthreads();

    if (w == 0 && lane == 0) {
        float llh = part[0] + part[1] + part[2] - logZ;
        atomicAdd(out, llh * (-1.f / 64.f));
    }
}

extern "C" void kernel_launch(void* const* d_in, const int* in_sizes, int n_in,
                              void* d_out, int out_size, void* d_ws, size_t ws_size,
                              hipStream_t stream) {
    const float* hidden = (const float*)d_in[0];
    const float* W      = (const float*)d_in[1];
    const float* bias   = (const float*)d_in[2];
    const float* st     = (const float*)d_in[3];
    const float* et     = (const float*)d_in[4];
    const float* T      = (const float*)d_in[5];
    const int*   labels = (const int*)d_in[6];
    const int*   mask   = (const int*)d_in[7];

    float* emis = (float*)d_ws;                 // 32768 * 9 floats
    float* outp = (float*)d_out;

    emis_kernel<<<512, 256, 0, stream>>>(hidden, W, bias, emis, outp);
    crf_kernel<<<Bn, 256, 0, stream>>>(emis, st, et, T, labels, mask, outp);
}